// Round 1
// baseline (785.591 us; speedup 1.0000x reference)
//
#include <hip/hip_runtime.h>
#include <stdint.h>

// B=4 T=4096 C=1024 H=16 HS=64 K=256(low rank)
typedef __attribute__((ext_vector_type(8))) short bf16x8;
typedef __attribute__((ext_vector_type(4))) float f32x4;
typedef __attribute__((ext_vector_type(4))) unsigned short us4;

__device__ __forceinline__ unsigned short f2bf(float f){
  unsigned int u = __float_as_uint(f);
  u += 0x7FFFu + ((u >> 16) & 1u);           // RNE
  return (unsigned short)(u >> 16);
}

__device__ __forceinline__ void gload16(const void* g, void* l){
  __builtin_amdgcn_global_load_lds((const __attribute__((address_space(1))) void*)g,
                                   (__attribute__((address_space(3))) void*)l, 16, 0, 0);
}

// ---- fp32 -> bf16 pack, vectorized x4 ----
__global__ __launch_bounds__(256) void pack4_k(const float* __restrict__ src,
                                               unsigned short* __restrict__ dst, int n4){
  int i = blockIdx.x*256 + threadIdx.x;
  if (i >= n4) return;
  float4 v = ((const float4*)src)[i];
  us4 o; o.x=f2bf(v.x); o.y=f2bf(v.y); o.z=f2bf(v.z); o.w=f2bf(v.w);
  ((us4*)dst)[i] = o;
}

// ---- pack W1t[n][c] bf16, n = sec*1024 + h*64 + s  (B^T layout for GEMMs) ----
__global__ __launch_bounds__(256) void pack_w1t_k(const float* __restrict__ WQ,
    const float* __restrict__ WK, const float* __restrict__ WV,
    unsigned short* __restrict__ w1t){
  int i = blockIdx.x*256 + threadIdx.x;      // [0, 3072*1024)
  int n = i >> 10, c = i & 1023;
  int sec = n >> 10, hh = (n >> 6) & 15, s = n & 63;
  const float* W = (sec == 0) ? WQ : ((sec == 1) ? WK : WV);
  w1t[i] = f2bf(W[(hh*1024 + c)*64 + s]);
}

// ---- bt GEMM: C[M][N] = A[M][K] * Bt[N][K]^T ; bf16 in, fp32 acc.
// 128x128 tile, BK=64, 4 waves 2x2, global_load_lds(16B) staging with
// XOR-16B-block swizzle (block j stored at j^(row&7)); single-buffered.
template<int OF32>
__global__ __launch_bounds__(256,2) void gemm_bt_k(
    const unsigned short* __restrict__ A, const unsigned short* __restrict__ Bt,
    void* __restrict__ Cout, const float* __restrict__ bias, int M, int N, int Kd)
{
  __shared__ unsigned short As[128*64];
  __shared__ unsigned short Bs[128*64];
  const int tid = threadIdx.x;
  const int w = tid >> 6, l = tid & 63;
  const int g = l >> 4, c16 = l & 15;
  const int m0 = blockIdx.y*128, n0 = blockIdx.x*128;
  const int wm = (w >> 1)*64, wn = (w & 1)*64;
  const int srow = l >> 3, sblk = l & 7;

  f32x4 acc[4][4];
  #pragma unroll
  for (int i=0;i<4;i++)
    #pragma unroll
    for (int j=0;j<4;j++) acc[i][j] = f32x4{0.f,0.f,0.f,0.f};

  for (int k0 = 0; k0 < Kd; k0 += 64){
    #pragma unroll
    for (int i=0;i<4;i++){
      int row = w*32 + i*8 + srow;
      int jb = sblk ^ (row & 7);
      gload16(A  + (size_t)(m0+row)*Kd + k0 + jb*8, (char*)As + (w*32+i*8)*128);
      gload16(Bt + (size_t)(n0+row)*Kd + k0 + jb*8, (char*)Bs + (w*32+i*8)*128);
    }
    __syncthreads();
    #pragma unroll
    for (int kk=0; kk<2; kk++){
      bf16x8 af[4], bfr[4];
      #pragma unroll
      for (int mt=0; mt<4; mt++){
        int row = wm + mt*16 + c16;
        af[mt] = *(const bf16x8*)((const char*)As + row*128 + (((kk*4+g) ^ (row&7))*16));
      }
      #pragma unroll
      for (int nt=0; nt<4; nt++){
        int row = wn + nt*16 + c16;
        bfr[nt] = *(const bf16x8*)((const char*)Bs + row*128 + (((kk*4+g) ^ (row&7))*16));
      }
      #pragma unroll
      for (int mt=0; mt<4; mt++)
        #pragma unroll
        for (int nt=0; nt<4; nt++)
          acc[mt][nt] = __builtin_amdgcn_mfma_f32_16x16x32_bf16(af[mt], bfr[nt], acc[mt][nt], 0,0,0);
    }
    __syncthreads();
  }
  #pragma unroll
  for (int mt=0; mt<4; mt++)
    #pragma unroll
    for (int nt=0; nt<4; nt++)
      #pragma unroll
      for (int r=0; r<4; r++){
        int row = m0 + wm + mt*16 + g*4 + r;
        int col = n0 + wn + nt*16 + c16;
        float v = acc[mt][nt][r];
        if (OF32) ((float*)Cout)[(size_t)row*N + col] = v + bias[col];
        else ((unsigned short*)Cout)[(size_t)row*N + col] = f2bf(v);
      }
}

// ---- E-projection: kp/vp[pair][256r][64s] partial sums over T (split-K 8x512).
// A = E^T via direct coalesced fp32 global loads (cvt->bf16 in reg);
// B = kvT rows staged to LDS [128c][32t] via gload_lds w/ ((c>>1)&3) block swizzle.
__global__ __launch_bounds__(256,2) void eproj_k(
    const float* __restrict__ E, const unsigned short* __restrict__ kvT,
    float* __restrict__ kpacc, float* __restrict__ vpacc)
{
  __shared__ unsigned short Bs[128*32];
  const int tid = threadIdx.x;
  const int w = tid >> 6, l = tid & 63;
  const int g = l >> 4, c16 = l & 15;
  const int pair = blockIdx.x, split = blockIdx.y;   // pair = h*4+b
  const int h = pair >> 2, b = pair & 3;
  const float* Eb = E + (size_t)pair*4096*256;

  f32x4 acc[4][8];
  #pragma unroll
  for (int i=0;i<4;i++)
    #pragma unroll
    for (int j=0;j<8;j++) acc[i][j] = f32x4{0.f,0.f,0.f,0.f};

  for (int step=0; step<16; step++){
    int t0 = split*512 + step*32;
    #pragma unroll
    for (int i=0;i<2;i++){
      int c = w*32 + i*16 + (l>>2);
      int row = (c < 64) ? (h*64 + c) : (960 + h*64 + c);  // k rows / v rows(+1024)
      int jb = (l&3) ^ ((c>>1)&3);
      gload16(kvT + (size_t)row*16384 + b*4096 + t0 + jb*8, (char*)Bs + (w*32+i*16)*64);
    }
    __syncthreads();
    bf16x8 af[4];
    #pragma unroll
    for (int mt=0; mt<4; mt++){
      int r = w*64 + mt*16 + c16;
      const float* ep = Eb + (size_t)(t0 + g*8)*256 + r;
      #pragma unroll
      for (int j=0;j<8;j++) af[mt][j] = (short)f2bf(ep[(size_t)j*256]);
    }
    #pragma unroll
    for (int nt=0; nt<8; nt++){
      int c = nt*16 + c16;
      bf16x8 bfr = *(const bf16x8*)((const char*)Bs + c*64 + ((g ^ ((c>>1)&3))*16));
      #pragma unroll
      for (int mt=0; mt<4; mt++)
        acc[mt][nt] = __builtin_amdgcn_mfma_f32_16x16x32_bf16(af[mt], bfr, acc[mt][nt], 0,0,0);
    }
    __syncthreads();
  }
  #pragma unroll
  for (int mt=0; mt<4; mt++)
    #pragma unroll
    for (int nt=0; nt<8; nt++)
      #pragma unroll
      for (int r2=0; r2<4; r2++){
        int r = w*64 + mt*16 + g*4 + r2;
        int c = nt*16 + c16;
        float v = acc[mt][nt][r2];
        if (c < 64) atomicAdd(kpacc + ((size_t)pair*256 + r)*64 + c, v);
        else        atomicAdd(vpacc + ((size_t)pair*256 + r)*64 + (c - 64), v);
      }
}

// ---- finalize: kp bf16 (*1/16 softmax scale folded), vp -> vpT bf16 ----
__global__ __launch_bounds__(256) void finalize_k(const float* __restrict__ kpacc,
    const float* __restrict__ vpacc, unsigned short* __restrict__ kp,
    unsigned short* __restrict__ vpT){
  int i = blockIdx.x*256 + threadIdx.x;   // [0, 64*256*64)
  int pair = i >> 14, r = (i >> 6) & 255, s = i & 63;
  kp[i] = f2bf(kpacc[i] * 0.0625f);
  vpT[(((size_t)pair*64 + s) << 8) + r] = f2bf(vpacc[i]);
}

// ---- attention: per block (pair, 128-row chunk), 8 waves x 16 rows.
// S = q*kp^T (scaled kp), causal-lowrank mask (r<=t), wave-parallel softmax,
// P via swizzled per-wave LDS, O = P*vp using vpT. Writes attn bf16 [16384][1024].
__global__ __launch_bounds__(512,2) void attn_k(
    const unsigned short* __restrict__ q, const unsigned short* __restrict__ kp,
    const unsigned short* __restrict__ vpT, unsigned short* __restrict__ attn)
{
  __shared__ unsigned short kps[256*64];   // 32KB, 128B rows, blk^= (r&7)
  __shared__ unsigned short vps[64*256];   // 32KB, 512B rows, blk^= (s&7)
  __shared__ unsigned short Ps[8][16*256]; // 64KB per-wave P, 512B rows, blk^= (t&7)
  const int tid = threadIdx.x;
  const int w = tid >> 6, l = tid & 63;
  const int g = l >> 4, c16 = l & 15;
  const int pair = blockIdx.x >> 5, chunk = blockIdx.x & 31;
  const int h = pair >> 2, b = pair & 3;
  const unsigned short* kpg = kp + (size_t)pair*256*64;
  const unsigned short* vpg = vpT + (size_t)pair*64*256;
  #pragma unroll
  for (int i=0;i<4;i++){
    int r = w*32 + i*8 + (l>>3);
    int jb = (l&7) ^ (r&7);
    gload16(kpg + r*64 + jb*8, (char*)kps + (w*32+i*8)*128);
  }
  #pragma unroll
  for (int i=0;i<4;i++){
    int s = w*8 + i*2 + (l>>5);
    int jb = (l&31) ^ (s&7);
    gload16(vpg + s*256 + jb*8, (char*)vps + (w*8+i*2)*512);
  }
  __syncthreads();

  const int tseq = chunk*128 + w*16;
  const unsigned short* qp = q + ((size_t)(b*4096 + tseq + c16))*1024 + h*64;
  bf16x8 qa[2];
  qa[0] = *(const bf16x8*)(qp + g*8);
  qa[1] = *(const bf16x8*)(qp + 32 + g*8);

  f32x4 sa[16];
  #pragma unroll
  for (int i=0;i<16;i++) sa[i] = f32x4{0.f,0.f,0.f,0.f};
  #pragma unroll
  for (int nt=0; nt<16; nt++){
    #pragma unroll
    for (int kk=0; kk<2; kk++){
      int r = nt*16 + c16;
      bf16x8 bfr = *(const bf16x8*)((const char*)kps + r*128 + (((kk*4+g) ^ (r&7))*16));
      sa[nt] = __builtin_amdgcn_mfma_f32_16x16x32_bf16(qa[kk], bfr, sa[nt], 0,0,0);
    }
  }
  // masked softmax over 256 compressed slots for each of this lane's 4 rows
  #pragma unroll
  for (int reg=0; reg<4; reg++){
    const int tg = tseq + g*4 + reg;
    float m = -3.0e38f;
    #pragma unroll
    for (int nt=0; nt<16; nt++){
      int r = nt*16 + c16;
      float v = (r <= tg) ? sa[nt][reg] : -3.0e38f;
      sa[nt][reg] = v;
      m = fmaxf(m, v);
    }
    #pragma unroll
    for (int d=1; d<16; d<<=1) m = fmaxf(m, __shfl_xor(m, d, 64));
    float ssum = 0.f;
    #pragma unroll
    for (int nt=0; nt<16; nt++){
      float p = __expf(sa[nt][reg] - m);
      sa[nt][reg] = p; ssum += p;
    }
    #pragma unroll
    for (int d=1; d<16; d<<=1) ssum += __shfl_xor(ssum, d, 64);
    float inv = 1.f / ssum;
    #pragma unroll
    for (int nt=0; nt<16; nt++) sa[nt][reg] *= inv;
  }
  // P -> per-wave LDS (bf16, swizzled)
  unsigned short* pw = &Ps[w][0];
  #pragma unroll
  for (int nt=0; nt<16; nt++){
    #pragma unroll
    for (int reg=0; reg<4; reg++){
      int tl = g*4 + reg;
      int r = nt*16 + c16;
      *(unsigned short*)((char*)pw + tl*512 + (((r>>3) ^ (tl&7))*16) + (r&7)*2) = f2bf(sa[nt][reg]);
    }
  }
  __syncthreads();
  // O = P * vp
  f32x4 oa[4];
  #pragma unroll
  for (int i=0;i<4;i++) oa[i] = f32x4{0.f,0.f,0.f,0.f};
  #pragma unroll
  for (int kk=0; kk<8; kk++){
    bf16x8 pa = *(const bf16x8*)((const char*)pw + c16*512 + (((kk*4+g) ^ (c16&7))*16));
    #pragma unroll
    for (int nt=0; nt<4; nt++){
      int s = nt*16 + c16;
      bf16x8 vb = *(const bf16x8*)((const char*)vps + s*512 + (((kk*4+g) ^ (s&7))*16));
      oa[nt] = __builtin_amdgcn_mfma_f32_16x16x32_bf16(pa, vb, oa[nt], 0,0,0);
    }
  }
  unsigned short* ap = attn + ((size_t)(b*4096 + tseq))*1024 + h*64;
  #pragma unroll
  for (int nt=0; nt<4; nt++)
    #pragma unroll
    for (int reg=0; reg<4; reg++){
      int tl = g*4 + reg;
      ap[(size_t)tl*1024 + nt*16 + c16] = f2bf(oa[nt][reg]);
    }
}

extern "C" void kernel_launch(void* const* d_in, const int* in_sizes, int n_in,
                              void* d_out, int out_size, void* d_ws, size_t ws_size,
                              hipStream_t stream)
{
  const float* x  = (const float*)d_in[0];
  const float* WQ = (const float*)d_in[1];
  const float* WK = (const float*)d_in[2];
  const float* WV = (const float*)d_in[3];
  const float* E  = (const float*)d_in[4];
  const float* Wp = (const float*)d_in[5];
  const float* bp = (const float*)d_in[6];
  float* out = (float*)d_out;
  (void)in_sizes; (void)n_in; (void)out_size; (void)ws_size;

  char* ws = (char*)d_ws;
  size_t off = 0;
  auto alloc = [&](size_t bytes)->char*{ char* p = ws + off; off += (bytes + 255) & ~(size_t)255; return p; };
  unsigned short* xb    = (unsigned short*)alloc((size_t)16384*1024*2); // x bf16
  unsigned short* w1t   = (unsigned short*)alloc((size_t)3072*1024*2);  // [q|k|v]^T weights bf16
  unsigned short* wpb   = (unsigned short*)alloc((size_t)1024*1024*2);  // Wp bf16 (already [n][k])
  unsigned short* qb    = (unsigned short*)alloc((size_t)16384*1024*2); // q [16384][1024]
  unsigned short* kvT   = (unsigned short*)alloc((size_t)2048*16384*2); // k,v transposed [2048][16384]
  float*          kpacc = (float*)alloc((size_t)64*256*64*4);
  float*          vpacc = (float*)alloc((size_t)64*256*64*4);
  unsigned short* kp    = (unsigned short*)alloc((size_t)64*256*64*2);  // [pair][256][64]
  unsigned short* vpT   = (unsigned short*)alloc((size_t)64*64*256*2);  // [pair][64][256]
  unsigned short* attn  = (unsigned short*)alloc((size_t)16384*1024*2); // pre-projection out

  pack4_k<<<16384, 256, 0, stream>>>(x, xb, 16384*1024/4);
  pack4_k<<<1024, 256, 0, stream>>>(Wp, wpb, 1024*1024/4);
  pack_w1t_k<<<12288, 256, 0, stream>>>(WQ, WK, WV, w1t);

  // q = x * Wq^T   (M=16384,N=1024,K=1024)
  gemm_bt_k<0><<<dim3(8,128), 256, 0, stream>>>(xb, w1t, qb, nullptr, 16384, 1024, 1024);
  // kvT = Wkv * x^T (M=2048,N=16384,K=1024)
  gemm_bt_k<0><<<dim3(128,16), 256, 0, stream>>>(w1t + (size_t)1024*1024, xb, kvT, nullptr, 2048, 16384, 1024);

  hipMemsetAsync(kpacc, 0, (size_t)64*256*64*4*2, stream);  // kpacc+vpacc contiguous
  eproj_k<<<dim3(64,8), 256, 0, stream>>>(E, kvT, kpacc, vpacc);
  finalize_k<<<4096, 256, 0, stream>>>(kpacc, vpacc, kp, vpT);

  attn_k<<<2048, 512, 0, stream>>>(qb, kp, vpT, attn);

  // out = attn * Wp^T + bp  (fp32 out)
  gemm_bt_k<1><<<dim3(8,128), 256, 0, stream>>>(attn, wpb, out, bp, 16384, 1024, 1024);
}

// Round 3
// 762.944 us; speedup vs baseline: 1.0297x; 1.0297x over previous
//
#include <hip/hip_runtime.h>
#include <stdint.h>

// B=4 T=4096 C=1024 H=16 HS=64 K=256(low rank)
typedef __attribute__((ext_vector_type(8))) short bf16x8;
typedef __attribute__((ext_vector_type(4))) float f32x4;
typedef __attribute__((ext_vector_type(4))) unsigned short us4;

__device__ __forceinline__ unsigned short f2bf(float f){
  unsigned int u = __float_as_uint(f);
  u += 0x7FFFu + ((u >> 16) & 1u);           // RNE
  return (unsigned short)(u >> 16);
}

__device__ __forceinline__ void gload16(const void* g, void* l){
  __builtin_amdgcn_global_load_lds((const __attribute__((address_space(1))) void*)g,
                                   (__attribute__((address_space(3))) void*)l, 16, 0, 0);
}

// ---- fp32 -> bf16 pack, vectorized x4 ----
__global__ __launch_bounds__(256) void pack4_k(const float* __restrict__ src,
                                               unsigned short* __restrict__ dst, int n4){
  int i = blockIdx.x*256 + threadIdx.x;
  if (i >= n4) return;
  float4 v = ((const float4*)src)[i];
  us4 o; o.x=f2bf(v.x); o.y=f2bf(v.y); o.z=f2bf(v.z); o.w=f2bf(v.w);
  ((us4*)dst)[i] = o;
}

// ---- pack W1t[n][c] bf16: n<1024 -> q rows (h*64+s); n>=1024 -> kv rows
// ordered h*128 + kv*64 + s so each head's k|v panel is contiguous. ----
__global__ __launch_bounds__(256) void pack_w1t_k(const float* __restrict__ WQ,
    const float* __restrict__ WK, const float* __restrict__ WV,
    unsigned short* __restrict__ w1t){
  int i = blockIdx.x*256 + threadIdx.x;      // [0, 3072*1024)
  int n = i >> 10, c = i & 1023;
  const float* W; int h, s;
  if (n < 1024){ h = n >> 6; s = n & 63; W = WQ; }
  else { int m = n - 1024; h = m >> 7; s = m & 63; W = ((m >> 6) & 1) ? WV : WK; }
  w1t[i] = f2bf(W[(h*1024 + c)*64 + s]);
}

// ---- E transpose+pack: fp32 [pair][4096t][256r] -> bf16 EbT [pair][256r][4096t].
// 64x64 LDS tile; coalesced float4 reads, coalesced 8B writes. ----
__global__ __launch_bounds__(256) void etrans_k(const float* __restrict__ E,
                                                unsigned short* __restrict__ EbT){
  __shared__ unsigned short L[64][66];
  const int tb = blockIdx.x, rb = blockIdx.y, pair = blockIdx.z;
  const float* src = E + ((size_t)pair*4096 + tb*64)*256 + rb*64;
  const int tt = threadIdx.x >> 2;
  const int r4 = (threadIdx.x & 3) * 16;
  const float4* s4 = (const float4*)(src + (size_t)tt*256 + r4);
  #pragma unroll
  for (int i=0;i<4;i++){
    float4 v = s4[i];
    L[tt][r4+i*4+0]=f2bf(v.x); L[tt][r4+i*4+1]=f2bf(v.y);
    L[tt][r4+i*4+2]=f2bf(v.z); L[tt][r4+i*4+3]=f2bf(v.w);
  }
  __syncthreads();
  const int rr = threadIdx.x >> 2;
  const int t4 = (threadIdx.x & 3) * 16;
  unsigned short* dst = EbT + ((size_t)(pair*256 + rb*64 + rr))*4096 + tb*64 + t4;
  #pragma unroll
  for (int i=0;i<4;i++){
    us4 o;
    o.x = L[t4+i*4+0][rr]; o.y = L[t4+i*4+1][rr];
    o.z = L[t4+i*4+2][rr]; o.w = L[t4+i*4+3][rr];
    ((us4*)dst)[i] = o;
  }
}

// ---- bt GEMM: C[M][N] = A[M][K] * Bt[N][K]^T ; bf16 in, fp32 acc.
// 128x128 tile, BK=64, 4 waves 2x2, global_load_lds(16B) staging with
// XOR-16B-block swizzle; XCD-aware block swizzle (grids are %8==0). ----
template<int OF32>
__global__ __launch_bounds__(256,2) void gemm_bt_k(
    const unsigned short* __restrict__ A, const unsigned short* __restrict__ Bt,
    void* __restrict__ Cout, const float* __restrict__ bias, int M, int N, int Kd)
{
  __shared__ unsigned short As[128*64];
  __shared__ unsigned short Bs[128*64];
  const int tid = threadIdx.x;
  const int w = tid >> 6, l = tid & 63;
  const int g = l >> 4, c16 = l & 15;
  // XCD swizzle: consecutive work ids stay on one XCD's L2
  int nwg = gridDim.x*gridDim.y;
  int orig = blockIdx.y*gridDim.x + blockIdx.x;
  int id = (orig & 7)*(nwg >> 3) + (orig >> 3);
  const int m0 = (id / gridDim.x)*128, n0 = (id % gridDim.x)*128;
  const int wm = (w >> 1)*64, wn = (w & 1)*64;
  const int srow = l >> 3, sblk = l & 7;

  f32x4 acc[4][4];
  #pragma unroll
  for (int i=0;i<4;i++)
    #pragma unroll
    for (int j=0;j<4;j++) acc[i][j] = f32x4{0.f,0.f,0.f,0.f};

  for (int k0 = 0; k0 < Kd; k0 += 64){
    #pragma unroll
    for (int i=0;i<4;i++){
      int row = w*32 + i*8 + srow;
      int jb = sblk ^ (row & 7);
      gload16(A  + (size_t)(m0+row)*Kd + k0 + jb*8, (char*)As + (w*32+i*8)*128);
      gload16(Bt + (size_t)(n0+row)*Kd + k0 + jb*8, (char*)Bs + (w*32+i*8)*128);
    }
    __syncthreads();
    #pragma unroll
    for (int kk=0; kk<2; kk++){
      bf16x8 af[4], bfr[4];
      #pragma unroll
      for (int mt=0; mt<4; mt++){
        int row = wm + mt*16 + c16;
        af[mt] = *(const bf16x8*)((const char*)As + row*128 + (((kk*4+g) ^ (row&7))*16));
      }
      #pragma unroll
      for (int nt=0; nt<4; nt++){
        int row = wn + nt*16 + c16;
        bfr[nt] = *(const bf16x8*)((const char*)Bs + row*128 + (((kk*4+g) ^ (row&7))*16));
      }
      #pragma unroll
      for (int mt=0; mt<4; mt++)
        #pragma unroll
        for (int nt=0; nt<4; nt++)
          acc[mt][nt] = __builtin_amdgcn_mfma_f32_16x16x32_bf16(af[mt], bfr[nt], acc[mt][nt], 0,0,0);
    }
    __syncthreads();
  }
  #pragma unroll
  for (int mt=0; mt<4; mt++)
    #pragma unroll
    for (int nt=0; nt<4; nt++)
      #pragma unroll
      for (int r=0; r<4; r++){
        int row = m0 + wm + mt*16 + g*4 + r;
        int col = n0 + wn + nt*16 + c16;
        float v = acc[mt][nt][r];
        if (OF32) ((float*)Cout)[(size_t)row*N + col] = v + bias[col];
        else ((unsigned short*)Cout)[(size_t)row*N + col] = f2bf(v);
      }
}

// ---- E-projection v2: gemm_bt clone. A=EbT[pair][256][4096], B=kvT rows
// h*128..h*128+127 (contiguous), cols b*4096+sp*1024+k. Output: fp32
// atomicAdd into kpvacc[pair][256r][128c] over 4 t-splits. ----
__global__ __launch_bounds__(256,2) void eproj2_k(
    const unsigned short* __restrict__ EbT, const unsigned short* __restrict__ kvT,
    float* __restrict__ kpvacc)
{
  __shared__ unsigned short As[128*64];
  __shared__ unsigned short Bs[128*64];
  const int tid = threadIdx.x;
  const int w = tid >> 6, l = tid & 63;
  const int g = l >> 4, c16 = l & 15;
  const int sp = blockIdx.x, mh = blockIdx.y, pair = blockIdx.z;
  const int h = pair >> 2, b = pair & 3;
  const unsigned short* Abase = EbT + ((size_t)(pair*256 + mh*128))*4096 + sp*1024;
  const unsigned short* Bbase = kvT + ((size_t)(h*128))*16384 + b*4096 + sp*1024;
  const int wm = (w >> 1)*64, wn = (w & 1)*64;
  const int srow = l >> 3, sblk = l & 7;

  f32x4 acc[4][4];
  #pragma unroll
  for (int i=0;i<4;i++)
    #pragma unroll
    for (int j=0;j<4;j++) acc[i][j] = f32x4{0.f,0.f,0.f,0.f};

  for (int k0 = 0; k0 < 1024; k0 += 64){
    #pragma unroll
    for (int i=0;i<4;i++){
      int row = w*32 + i*8 + srow;
      int jb = sblk ^ (row & 7);
      gload16(Abase + (size_t)row*4096  + k0 + jb*8, (char*)As + (w*32+i*8)*128);
      gload16(Bbase + (size_t)row*16384 + k0 + jb*8, (char*)Bs + (w*32+i*8)*128);
    }
    __syncthreads();
    #pragma unroll
    for (int kk=0; kk<2; kk++){
      bf16x8 af[4], bfr[4];
      #pragma unroll
      for (int mt=0; mt<4; mt++){
        int row = wm + mt*16 + c16;
        af[mt] = *(const bf16x8*)((const char*)As + row*128 + (((kk*4+g) ^ (row&7))*16));
      }
      #pragma unroll
      for (int nt=0; nt<4; nt++){
        int row = wn + nt*16 + c16;
        bfr[nt] = *(const bf16x8*)((const char*)Bs + row*128 + (((kk*4+g) ^ (row&7))*16));
      }
      #pragma unroll
      for (int mt=0; mt<4; mt++)
        #pragma unroll
        for (int nt=0; nt<4; nt++)
          acc[mt][nt] = __builtin_amdgcn_mfma_f32_16x16x32_bf16(af[mt], bfr[nt], acc[mt][nt], 0,0,0);
    }
    __syncthreads();
  }
  float* C = kpvacc + (size_t)(pair*256 + mh*128)*128;
  #pragma unroll
  for (int mt=0; mt<4; mt++)
    #pragma unroll
    for (int nt=0; nt<4; nt++)
      #pragma unroll
      for (int r=0; r<4; r++)
        atomicAdd(C + (size_t)(wm + mt*16 + g*4 + r)*128 + wn + nt*16 + c16, acc[mt][nt][r]);
}

// ---- finalize: kpvacc[pair][256r][128c] -> kp bf16 (c<64, *1/16 folded),
// vpT bf16 [pair][64s][256r] (c>=64) ----
__global__ __launch_bounds__(256) void finalize2_k(const float* __restrict__ kpvacc,
    unsigned short* __restrict__ kp, unsigned short* __restrict__ vpT){
  int i = blockIdx.x*256 + threadIdx.x;   // [0, 64*256*128)
  int pair = i >> 15, r = (i >> 7) & 255, c = i & 127;
  float v = kpvacc[i];
  if (c < 64) kp[((size_t)pair*256 + r)*64 + c] = f2bf(v * 0.0625f);
  else        vpT[((size_t)pair*64 + (c - 64))*256 + r] = f2bf(v);
}

// ---- attention: per block (pair, 128-row chunk), 8 waves x 16 rows. ----
__global__ __launch_bounds__(512,2) void attn_k(
    const unsigned short* __restrict__ q, const unsigned short* __restrict__ kp,
    const unsigned short* __restrict__ vpT, unsigned short* __restrict__ attn)
{
  __shared__ unsigned short kps[256*64];   // 32KB, 128B rows, blk^= (r&7)
  __shared__ unsigned short vps[64*256];   // 32KB, 512B rows, blk^= (s&7)
  __shared__ unsigned short Ps[8][16*256]; // 64KB per-wave P, 512B rows, blk^= (t&7)
  const int tid = threadIdx.x;
  const int w = tid >> 6, l = tid & 63;
  const int g = l >> 4, c16 = l & 15;
  const int pair = blockIdx.x >> 5, chunk = blockIdx.x & 31;
  const int h = pair >> 2, b = pair & 3;
  const unsigned short* kpg = kp + (size_t)pair*256*64;
  const unsigned short* vpg = vpT + (size_t)pair*64*256;
  #pragma unroll
  for (int i=0;i<4;i++){
    int r = w*32 + i*8 + (l>>3);
    int jb = (l&7) ^ (r&7);
    gload16(kpg + r*64 + jb*8, (char*)kps + (w*32+i*8)*128);
  }
  #pragma unroll
  for (int i=0;i<4;i++){
    int s = w*8 + i*2 + (l>>5);
    int jb = (l&31) ^ (s&7);
    gload16(vpg + s*256 + jb*8, (char*)vps + (w*8+i*2)*512);
  }
  __syncthreads();

  const int tseq = chunk*128 + w*16;
  const unsigned short* qp = q + ((size_t)(b*4096 + tseq + c16))*1024 + h*64;
  bf16x8 qa[2];
  qa[0] = *(const bf16x8*)(qp + g*8);
  qa[1] = *(const bf16x8*)(qp + 32 + g*8);

  f32x4 sa[16];
  #pragma unroll
  for (int i=0;i<16;i++) sa[i] = f32x4{0.f,0.f,0.f,0.f};
  #pragma unroll
  for (int nt=0; nt<16; nt++){
    #pragma unroll
    for (int kk=0; kk<2; kk++){
      int r = nt*16 + c16;
      bf16x8 bfr = *(const bf16x8*)((const char*)kps + r*128 + (((kk*4+g) ^ (r&7))*16));
      sa[nt] = __builtin_amdgcn_mfma_f32_16x16x32_bf16(qa[kk], bfr, sa[nt], 0,0,0);
    }
  }
  #pragma unroll
  for (int reg=0; reg<4; reg++){
    const int tg = tseq + g*4 + reg;
    float m = -3.0e38f;
    #pragma unroll
    for (int nt=0; nt<16; nt++){
      int r = nt*16 + c16;
      float v = (r <= tg) ? sa[nt][reg] : -3.0e38f;
      sa[nt][reg] = v;
      m = fmaxf(m, v);
    }
    #pragma unroll
    for (int d=1; d<16; d<<=1) m = fmaxf(m, __shfl_xor(m, d, 64));
    float ssum = 0.f;
    #pragma unroll
    for (int nt=0; nt<16; nt++){
      float p = __expf(sa[nt][reg] - m);
      sa[nt][reg] = p; ssum += p;
    }
    #pragma unroll
    for (int d=1; d<16; d<<=1) ssum += __shfl_xor(ssum, d, 64);
    float inv = 1.f / ssum;
    #pragma unroll
    for (int nt=0; nt<16; nt++) sa[nt][reg] *= inv;
  }
  unsigned short* pw = &Ps[w][0];
  #pragma unroll
  for (int nt=0; nt<16; nt++){
    #pragma unroll
    for (int reg=0; reg<4; reg++){
      int tl = g*4 + reg;
      int r = nt*16 + c16;
      *(unsigned short*)((char*)pw + tl*512 + (((r>>3) ^ (tl&7))*16) + (r&7)*2) = f2bf(sa[nt][reg]);
    }
  }
  __syncthreads();
  f32x4 oa[4];
  #pragma unroll
  for (int i=0;i<4;i++) oa[i] = f32x4{0.f,0.f,0.f,0.f};
  #pragma unroll
  for (int kk=0; kk<8; kk++){
    bf16x8 pa = *(const bf16x8*)((const char*)pw + c16*512 + (((kk*4+g) ^ (c16&7))*16));
    #pragma unroll
    for (int nt=0; nt<4; nt++){
      int s = nt*16 + c16;
      bf16x8 vb = *(const bf16x8*)((const char*)vps + s*512 + (((kk*4+g) ^ (s&7))*16));
      oa[nt] = __builtin_amdgcn_mfma_f32_16x16x32_bf16(pa, vb, oa[nt], 0,0,0);
    }
  }
  unsigned short* ap = attn + ((size_t)(b*4096 + tseq))*1024 + h*64;
  #pragma unroll
  for (int nt=0; nt<4; nt++)
    #pragma unroll
    for (int reg=0; reg<4; reg++){
      int tl = g*4 + reg;
      ap[(size_t)tl*1024 + nt*16 + c16] = f2bf(oa[nt][reg]);
    }
}

extern "C" void kernel_launch(void* const* d_in, const int* in_sizes, int n_in,
                              void* d_out, int out_size, void* d_ws, size_t ws_size,
                              hipStream_t stream)
{
  const float* x  = (const float*)d_in[0];
  const float* WQ = (const float*)d_in[1];
  const float* WK = (const float*)d_in[2];
  const float* WV = (const float*)d_in[3];
  const float* E  = (const float*)d_in[4];
  const float* Wp = (const float*)d_in[5];
  const float* bp = (const float*)d_in[6];
  float* out = (float*)d_out;
  (void)in_sizes; (void)n_in; (void)out_size; (void)ws_size;

  char* ws = (char*)d_ws;
  size_t off = 0;
  auto alloc = [&](size_t bytes)->char*{ char* p = ws + off; off += (bytes + 255) & ~(size_t)255; return p; };
  unsigned short* xb     = (unsigned short*)alloc((size_t)16384*1024*2); // x bf16
  unsigned short* w1t    = (unsigned short*)alloc((size_t)3072*1024*2);  // [q|kv]^T weights bf16
  unsigned short* wpb    = (unsigned short*)alloc((size_t)1024*1024*2);  // Wp bf16
  unsigned short* qb     = (unsigned short*)alloc((size_t)16384*1024*2); // q [16384][1024]
  unsigned short* kvT    = (unsigned short*)alloc((size_t)2048*16384*2); // k,v transposed [2048][16384]
  float*          kpvacc = (float*)alloc((size_t)64*256*128*4);          // 8 MB
  unsigned short* kp     = (unsigned short*)alloc((size_t)64*256*64*2);  // [pair][256][64]
  unsigned short* vpT    = (unsigned short*)alloc((size_t)64*64*256*2);  // [pair][64][256]
  unsigned short* EbT    = (unsigned short*)alloc((size_t)64*256*4096*2);// 128 MB, dead after eproj2
  unsigned short* attn   = EbT;                                          // alias (attn after eproj2)

  pack4_k<<<16384, 256, 0, stream>>>(x, xb, 16384*1024/4);
  pack4_k<<<1024, 256, 0, stream>>>(Wp, wpb, 1024*1024/4);
  pack_w1t_k<<<12288, 256, 0, stream>>>(WQ, WK, WV, w1t);
  etrans_k<<<dim3(64,4,64), 256, 0, stream>>>(E, EbT);

  // q = x * Wq^T   (M=16384,N=1024,K=1024)
  gemm_bt_k<0><<<dim3(8,128), 256, 0, stream>>>(xb, w1t, qb, nullptr, 16384, 1024, 1024);
  // kvT = Wkv * x^T (M=2048,N=16384,K=1024)
  gemm_bt_k<0><<<dim3(128,16), 256, 0, stream>>>(w1t + (size_t)1024*1024, xb, kvT, nullptr, 2048, 16384, 1024);

  hipMemsetAsync(kpvacc, 0, (size_t)64*256*128*4, stream);
  eproj2_k<<<dim3(4,2,64), 256, 0, stream>>>(EbT, kvT, kpvacc);
  finalize2_k<<<8192, 256, 0, stream>>>(kpvacc, kp, vpT);

  attn_k<<<2048, 512, 0, stream>>>(qb, kp, vpT, attn);

  // out = attn * Wp^T + bp  (fp32 out)
  gemm_bt_k<1><<<dim3(8,128), 256, 0, stream>>>(attn, wpb, out, bp, 16384, 1024, 1024);
}